// Round 12
// baseline (525.379 us; speedup 1.0000x reference)
//
#include <hip/hip_runtime.h>

#define HW 2304   // 48*48
#define NB (4 * 64 * HW)

typedef short s16x8 __attribute__((ext_vector_type(8)));
typedef float f32x4 __attribute__((ext_vector_type(4)));

static __device__ __forceinline__ unsigned short f2bf(float f) {
    unsigned u = __float_as_uint(f);
    unsigned r = (u + 0x7FFFu + ((u >> 16) & 1u)) >> 16;   // RNE
    return (unsigned short)r;
}

// ---------------------------------------------------------------------------
// Zero attb + accX + accA + accB (contiguous): 4349952 floats = 4248 blocks.
// ---------------------------------------------------------------------------
__global__ __launch_bounds__(256) void zero_kernel(float4* __restrict__ p) {
    p[blockIdx.x * 256 + threadIdx.x] = make_float4(0.f, 0.f, 0.f, 0.f);
}

// ---------------------------------------------------------------------------
// Sobel edge magnitude on x3 (C=1), SAME zero padding.  [4,48,48] -> [4,2304]
// ---------------------------------------------------------------------------
__global__ __launch_bounds__(256) void edge_kernel(const float* __restrict__ x3,
                                                   float* __restrict__ edge) {
    int idx = blockIdx.x * 256 + threadIdx.x;   // < 9216
    int b = idx / HW;
    int j = idx % HW;
    int y = j / 48, x = j % 48;
    const float* p = x3 + b * HW;
    auto at = [&](int yy, int xx) -> float {
        return (yy >= 0 && yy < 48 && xx >= 0 && xx < 48) ? p[yy * 48 + xx] : 0.f;
    };
    float a00 = at(y - 1, x - 1), a01 = at(y - 1, x), a02 = at(y - 1, x + 1);
    float a10 = at(y, x - 1),                         a12 = at(y, x + 1);
    float a20 = at(y + 1, x - 1), a21 = at(y + 1, x), a22 = at(y + 1, x + 1);
    float ex = (a02 - a00) + 2.f * (a12 - a10) + (a22 - a20);
    float ey = (a20 - a00) + 2.f * (a21 - a01) + (a22 - a02);
    edge[idx] = sqrtf(ex * ex + ey * ey);
}

// ---------------------------------------------------------------------------
// Single-stage conv body for small CIN (21/1): stage ALL cins once (one
// barrier pair), then an uninterrupted FMA run.  R12: the chunked version
// paid a vmcnt-drain barrier per 8 cins -> latency-bound at low occupancy.
// ---------------------------------------------------------------------------
template <int CIN, int NC>
__device__ __forceinline__ void conv_small_body(
    const float* __restrict__ in, const float* __restrict__ w,
    const float* __restrict__ bias,
    const float* __restrict__ bng, const float* __restrict__ bnb,
    const float* __restrict__ bnm, const float* __restrict__ bnv,
    float* __restrict__ out, int cg, int tile, int b) {
    const int tx0 = (tile % 3) * 16, ty0 = (tile / 3) * 16;
    const int tid = threadIdx.x;
    const int tx = tid & 15, ty = tid >> 4;

    __shared__ float sl[CIN * 360];
    const float* ip = in + (b * CIN) * HW;
    for (int e = tid; e < CIN * 324; e += 256) {
        int cl = e / 324; int r = e - cl * 324;
        int ly = r / 18;  int lx = r - ly * 18;
        int gy = ty0 + ly - 1, gx = tx0 + lx - 1;
        float v = 0.f;
        if (gy >= 0 && gy < 48 && gx >= 0 && gx < 48) v = ip[cl * HW + gy * 48 + gx];
        sl[cl * 360 + ly * 20 + lx] = v;
    }
    __syncthreads();

    float acc[NC];
#pragma unroll
    for (int k = 0; k < NC; ++k) acc[k] = 0.f;

#pragma unroll 1
    for (int cl = 0; cl < CIN; ++cl) {
        float xv[9];
#pragma unroll
        for (int dy = 0; dy < 3; dy++)
#pragma unroll
            for (int dx = 0; dx < 3; dx++)
                xv[dy * 3 + dx] = sl[cl * 360 + (ty + dy) * 20 + (tx + dx)];
#pragma unroll
        for (int k = 0; k < NC; ++k) {
            const float* wk = w + ((cg * NC + k) * CIN + cl) * 9;
            float a = acc[k];
#pragma unroll
            for (int d = 0; d < 9; ++d) a = fmaf(wk[d], xv[d], a);
            acc[k] = a;
        }
    }

    const int oy = ty0 + ty, ox = tx0 + tx;
#pragma unroll
    for (int k = 0; k < NC; ++k) {
        int o = cg * NC + k;
        float sc = bng[o] * rsqrtf(bnv[o] + 1e-5f);
        float sh = bnb[o] - bnm[o] * sc;
        float y = fmaf(acc[k] + bias[o], sc, sh);
        y = y > 0.f ? y : 0.01f * y;
        out[(b * 64 + o) * HW + oy * 48 + ox] = y;
    }
}

// Small first-layer convs (CIN 21/1): NC=2 -> grid 1152.
template <int CIN>
__global__ __launch_bounds__(256) void conv_first(
    const float* __restrict__ in, const float* __restrict__ w,
    const float* __restrict__ bias,
    const float* __restrict__ bng, const float* __restrict__ bnb,
    const float* __restrict__ bnm, const float* __restrict__ bnv,
    float* __restrict__ out) {
    int lb = blockIdx.x;
    int blk = (lb & 7) * 144 + (lb >> 3);   // 1152 = 8 * 144
    int cg = blk & 31, tile = (blk >> 5) % 9, b = blk / 288;
    conv_small_body<CIN, 2>(in, w, bias, bng, bnb, bnm, bnv, out, cg, tile, b);
}

// ---------------------------------------------------------------------------
// conv144_split: 4-way cin-split (36 each), single-stage (50.6 KB LDS, 3
// blocks/CU), raw partials atomicAdd'ed into zeroed accX; bn1 finishes.
// ---------------------------------------------------------------------------
__global__ __launch_bounds__(256) void conv144_split(
    const float* __restrict__ in, const float* __restrict__ w,
    float* __restrict__ acc_out) {
    int lb = blockIdx.x;
    int blk = (lb & 7) * 144 + (lb >> 3);   // 1152 = 8 * 144
    const int sp   = blk & 3;               // cin split (36 each)
    const int cg   = (blk >> 2) & 7;        // cout group of 8
    const int tile = (blk >> 5) % 9;
    const int b    = blk / 288;
    const int tx0 = (tile % 3) * 16, ty0 = (tile / 3) * 16;
    const int tid = threadIdx.x;
    const int tx = tid & 15, ty = tid >> 4;

    __shared__ float sl[36 * 360];          // 51840 B

    const float* inb_p = in + (b * 144 + sp * 36) * HW;
    for (int e = tid; e < 36 * 324; e += 256) {
        int cl = e / 324; int r = e - cl * 324;
        int ly = r / 18;  int lx = r - ly * 18;
        int gy = ty0 + ly - 1, gx = tx0 + lx - 1;
        float v = 0.f;
        if (gy >= 0 && gy < 48 && gx >= 0 && gx < 48)
            v = inb_p[cl * HW + gy * 48 + gx];
        sl[cl * 360 + ly * 20 + lx] = v;
    }
    __syncthreads();

    float acc[8];
#pragma unroll
    for (int k = 0; k < 8; ++k) acc[k] = 0.f;

#pragma unroll 1
    for (int g = 0; g < 4; ++g) {
#pragma unroll
        for (int c9 = 0; c9 < 9; ++c9) {
            int cl = g * 9 + c9;
            float xv[9];
#pragma unroll
            for (int dy = 0; dy < 3; dy++)
#pragma unroll
                for (int dx = 0; dx < 3; dx++)
                    xv[dy * 3 + dx] = sl[cl * 360 + (ty + dy) * 20 + (tx + dx)];
#pragma unroll
            for (int k = 0; k < 8; ++k) {
                const float* wk = w + ((cg * 8 + k) * 144 + sp * 36 + cl) * 9;
                float a = acc[k];
#pragma unroll
                for (int d = 0; d < 9; ++d) a = fmaf(wk[d], xv[d], a);
                acc[k] = a;
            }
        }
    }

    const int oy = ty0 + ty, ox = tx0 + tx;
#pragma unroll
    for (int k = 0; k < 8; ++k)
        atomicAdd(&acc_out[(b * 64 + cg * 8 + k) * HW + oy * 48 + ox], acc[k]);
}

// BN + LeakyReLU for the accumulated 144-conv.  589824 elems -> 2304 blocks.
__global__ __launch_bounds__(256) void bn1_kernel(
    const float* __restrict__ acc, const float* __restrict__ bias,
    const float* __restrict__ bng, const float* __restrict__ bnb,
    const float* __restrict__ bnm, const float* __restrict__ bnv,
    float* __restrict__ out) {
    int idx = blockIdx.x * 256 + threadIdx.x;
    int o = (idx / HW) & 63;
    float sc = bng[o] * rsqrtf(bnv[o] + 1e-5f);
    float sh = bnb[o] - bnm[o] * sc;
    float y = fmaf(acc[idx] + bias[o], sc, sh);
    out[idx] = y > 0.f ? y : 0.01f * y;
}

// ---------------------------------------------------------------------------
// conv64_split: 2-way cin-split (32 each), single-stage (45 KB LDS, 3
// blocks/CU), one barrier pair, 2304 uninterrupted FMAs; bn64 finishes.
// ---------------------------------------------------------------------------
__global__ __launch_bounds__(256) void conv64_split(
    const float* __restrict__ inA, const float* __restrict__ inB,
    const float* __restrict__ inC, float* __restrict__ acc_out,
    const float* __restrict__ Wm, int step) {
    int lb = blockIdx.x;
    int blk = (lb & 7) * 216 + (lb >> 3);  // 1728 = 8 * 216
    const int br = blk / 576;
    int rr = blk - br * 576;
    const int sp   = rr & 1;               // cin split (32 each)
    const int cg   = (rr >> 1) & 7;        // cout group of 8
    const int tile = (rr >> 4) % 9;
    const int b    = rr / 144;
    const int tx0 = (tile % 3) * 16, ty0 = (tile / 3) * 16;
    const int tid = threadIdx.x;
    const int tx = tid & 15, ty = tid >> 4;

    const float* in = (br == 0) ? inA : (br == 1) ? inB : inC;
    const float* w = Wm + (2 * br + step) * (64 * 64 * 9);

    __shared__ float sl[32 * 360];          // 46080 B

    const float* inb_p = in + (b * 64 + sp * 32) * HW;
    for (int e = tid; e < 32 * 324; e += 256) {
        int cl = e / 324; int r = e - cl * 324;
        int ly = r / 18;  int lx = r - ly * 18;
        int gy = ty0 + ly - 1, gx = tx0 + lx - 1;
        float v = 0.f;
        if (gy >= 0 && gy < 48 && gx >= 0 && gx < 48)
            v = inb_p[cl * HW + gy * 48 + gx];
        sl[cl * 360 + ly * 20 + lx] = v;
    }
    __syncthreads();

    float acc[8];
#pragma unroll
    for (int k = 0; k < 8; ++k) acc[k] = 0.f;

#pragma unroll 1
    for (int g = 0; g < 4; ++g) {
#pragma unroll
        for (int c8 = 0; c8 < 8; ++c8) {
            int cl = g * 8 + c8;
            float xv[9];
#pragma unroll
            for (int dy = 0; dy < 3; dy++)
#pragma unroll
                for (int dx = 0; dx < 3; dx++)
                    xv[dy * 3 + dx] = sl[cl * 360 + (ty + dy) * 20 + (tx + dx)];
#pragma unroll
            for (int k = 0; k < 8; ++k) {
                const float* wk = w + ((cg * 8 + k) * 64 + sp * 32 + cl) * 9;
                float a = acc[k];
#pragma unroll
                for (int d = 0; d < 9; ++d) a = fmaf(wk[d], xv[d], a);
                acc[k] = a;
            }
        }
    }

    const int oy = ty0 + ty, ox = tx0 + tx;
    float* dst = acc_out + br * NB + (b * 64 + cg * 8) * HW + oy * 48 + ox;
#pragma unroll
    for (int k = 0; k < 8; ++k)
        atomicAdd(dst + k * HW, acc[k]);
}

// BN + LeakyReLU for the accumulated 64-convs (3 branches).  Grid 6912.
__global__ __launch_bounds__(256) void bn64_kernel(
    const float* __restrict__ acc, const float* __restrict__ bm,
    const float* __restrict__ bng, const float* __restrict__ bnb,
    const float* __restrict__ bnm, const float* __restrict__ bnv, int step,
    float* __restrict__ oA, float* __restrict__ oB, float* __restrict__ oC) {
    int idx = blockIdx.x * 256 + threadIdx.x;   // < 3*NB
    int br = idx / NB;
    int rem = idx - br * NB;
    int oo = (2 * br + step) * 64 + ((rem / HW) & 63);
    float sc = bng[oo] * rsqrtf(bnv[oo] + 1e-5f);
    float sh = bnb[oo] - bnm[oo] * sc;
    float y = fmaf(acc[idx] + bm[oo], sc, sh);
    y = y > 0.f ? y : 0.01f * y;
    float* out = (br == 0) ? oA : (br == 1) ? oB : oC;
    out[rem] = y;
}

// ---------------------------------------------------------------------------
// value_r_kernel: value vectors (1x1 conv 64->8), squared norms, and the
// pre-swizzled transposed bf16 feature tensor dT[m][b][j][c] (row = 128 B).
// ---------------------------------------------------------------------------
__global__ __launch_bounds__(256) void value_r_kernel(
    const float* __restrict__ d1, const float* __restrict__ d2,
    const float* __restrict__ d3, const float* __restrict__ Wv,
    const float* __restrict__ bv, float* __restrict__ vbuf,
    float* __restrict__ rbuf, unsigned short* __restrict__ dT) {
    __shared__ float sWv[512];
    int blk = blockIdx.x;
    int jseg = blk % 36;
    int b = (blk / 36) % 4;
    int m = blk / 144;
    int tid = threadIdx.x;
    sWv[tid] = Wv[tid];
    if (tid < 256) sWv[tid + 256] = Wv[tid + 256];
    __syncthreads();

    int jl = tid >> 2, cp = tid & 3;
    int j = jseg * 64 + jl;
    const float* dm = (m == 0) ? d1 : (m == 1) ? d2 : d3;
    const float* dp = dm + (b * 64) * HW + j;
    float acc[8];
#pragma unroll
    for (int k = 0; k < 8; k++) acc[k] = 0.f;
    float r = 0.f;
    float x[16];
#pragma unroll
    for (int cc = 0; cc < 16; ++cc) {
        int c = cp * 16 + cc;
        float xv = dp[c * HW];
        x[cc] = xv;
        r = fmaf(xv, xv, r);
#pragma unroll
        for (int k = 0; k < 8; k++) acc[k] = fmaf(xv, sWv[k * 64 + c], acc[k]);
    }

    {
        unsigned wds[8];
#pragma unroll
        for (int t = 0; t < 8; ++t)
            wds[t] = (unsigned)f2bf(x[2 * t]) | ((unsigned)f2bf(x[2 * t + 1]) << 16);
        size_t rowb = ((size_t)(m * 4 + b) * HW + j) * 128;   // bytes
        int s = jl & 7;                                        // == j & 7
        uint4 p0 = make_uint4(wds[0], wds[1], wds[2], wds[3]);
        uint4 p1 = make_uint4(wds[4], wds[5], wds[6], wds[7]);
        *(uint4*)((char*)dT + rowb + (size_t)(((cp * 2) ^ s) * 16)) = p0;
        *(uint4*)((char*)dT + rowb + (size_t)(((cp * 2 + 1) ^ s) * 16)) = p1;
    }

    r += __shfl_xor(r, 1, 4);
    r += __shfl_xor(r, 2, 4);
    float* vp = vbuf + ((m * 4 + b) * HW + j) * 8;
#pragma unroll
    for (int k = 0; k < 8; k++) {
        float v = acc[k];
        v += __shfl_xor(v, 1, 4);
        v += __shfl_xor(v, 2, 4);
        if (cp == 0) vp[k] = v + bv[k];
    }
    if (cp == 0) rbuf[(m * 4 + b) * HW + j] = r;
}

// ---------------------------------------------------------------------------
// attn v5: MFMA Gram + VALU epilogue/PV.  R12: single-buffered FjT cuts LDS
// 75.6->49.9 KB -> 3 blocks/CU (was 2).  Schedule per subtile:
//   Gram-MFMA -> barrier (FjT reads done) -> issue stage(sub+1) ->
//   epilogue (overlaps stage latency) -> barrier.
// V/R stay double-buffered so the epilogue's reads don't conflict.
// ---------------------------------------------------------------------------
#define FJT   (smem)
#define FIT   (smem + 24576)
#define VJB(bi) ((float*)(smem + 36864 + (bi) * 6144))
#define RJB(bi) ((float*)(smem + 49152 + (bi) * 768))

__global__ __launch_bounds__(256, 2) void attn_kernel(
    const unsigned short* __restrict__ dT, const float* __restrict__ vbuf,
    const float* __restrict__ rbuf, const float* __restrict__ gam,
    float* __restrict__ attbuf) {
    __shared__ char smem[51072];
    float* Ri = (float*)(smem + 50688);  // 384 B

    int lb = blockIdx.x;
    int blk = (lb & 7) * 324 + (lb >> 3);
    const int js = blk % 9;
    const int it = (blk / 9) % 72;
    const int b  = blk / 648;
    const int i0 = it * 32;
    const int tid = threadIdx.x;
    const int lane = tid & 63;
    const int wv = tid >> 6;
    const int l15 = lane & 15, lg = lane >> 4;
    const int swz = l15 & 7;

    // ---- stage FiT (12 x 1KB) + Ri (once) ----
#pragma unroll
    for (int t = 0; t < 3; ++t) {
        int ck = wv * 3 + t;
        int m = ck >> 2; int off = (ck & 3) * 1024;
        const char* src = (const char*)dT +
            ((size_t)((m * 4 + b) * HW + i0) * 128) + off + lane * 16;
        __builtin_amdgcn_global_load_lds((const unsigned int*)src,
                                         (unsigned int*)(FIT + ck * 1024), 16, 0, 0);
    }
    if (tid < 96) {
        int m = tid >> 5, i = tid & 31;
        Ri[m * 32 + i] = rbuf[(m * 4 + b) * HW + i0 + i];
    }

    auto stage_tile = [&](int sub, int bi) {
        const int j0 = (js * 4 + sub) * 64;
#pragma unroll
        for (int t = 0; t < 8; ++t) {
            int idx = t * 4 + wv;
            if (idx < 24) {                      // FjT: 24 x 1KB (single buf)
                int m = idx >> 3; int off = (idx & 7) * 1024;
                const char* src = (const char*)dT +
                    ((size_t)((m * 4 + b) * HW + j0) * 128) + off + lane * 16;
                __builtin_amdgcn_global_load_lds((const unsigned int*)src,
                    (unsigned int*)(FJT + idx * 1024), 16, 0, 0);
            } else if (idx < 30) {               // Vj: 6 x 1KB (double buf)
                int c = idx - 24; int m = c >> 1; int off = (c & 1) * 1024;
                const char* src = (const char*)vbuf +
                    ((size_t)((m * 4 + b) * HW + j0) * 32) + off + lane * 16;
                __builtin_amdgcn_global_load_lds((const unsigned int*)src,
                    (unsigned int*)((char*)VJB(bi) + c * 1024), 16, 0, 0);
            }
        }
        if (tid < 192) {
            int m = tid >> 6, jl = tid & 63;
            RJB(bi)[m * 64 + jl] = rbuf[(m * 4 + b) * HW + j0 + jl];
        }
    };

    float g0 = gam[0], g1 = gam[1], g2 = gam[2];
    float inv0 = 1.f / (2.f * g0 * g0);
    float inv1 = 1.f / (2.f * g1 * g1);
    float inv2 = 1.f / (2.f * g2 * g2);
    float g6 = gam[6], g7 = gam[7], g8 = gam[8];
    float c00 = g6,       c01 = g7 + 1.f, c02 = g8 + 1.f;
    float c10 = g6 + 1.f, c11 = g7,       c12 = g8 + 1.f;
    float c20 = g6 + 1.f, c21 = g7 + 1.f, c22 = g8;

    stage_tile(0, 0);
    __syncthreads();    // drains global_load_lds

    float ri0[2], ri1[2], ri2[2];
#pragma unroll
    for (int ii = 0; ii < 2; ++ii) {
        ri0[ii] = Ri[0 * 32 + ii * 16 + l15];
        ri1[ii] = Ri[1 * 32 + ii * 16 + l15];
        ri2[ii] = Ri[2 * 32 + ii * 16 + l15];
    }

    float pv[3][2][8];
#pragma unroll
    for (int mp = 0; mp < 3; ++mp)
#pragma unroll
        for (int ii = 0; ii < 2; ++ii)
#pragma unroll
            for (int k = 0; k < 8; ++k) pv[mp][ii][k] = 0.f;

#pragma unroll 1
    for (int sub = 0; sub < 4; ++sub) {
        const int bi = sub & 1;

        // ---- Gram MFMA from the (single) FjT + FiT ----
        f32x4 g[3][2];
#pragma unroll
        for (int m = 0; m < 3; ++m)
#pragma unroll
            for (int ii = 0; ii < 2; ++ii) g[m][ii] = (f32x4){0.f, 0.f, 0.f, 0.f};

#pragma unroll
        for (int m = 0; m < 3; ++m) {
#pragma unroll
            for (int slab = 0; slab < 2; ++slab) {
                int ch = slab * 4 + lg;
                s16x8 a = *(const s16x8*)(FJT + m * 8192 +
                            (wv * 16 + l15) * 128 + ((ch ^ swz) * 16));
#pragma unroll
                for (int ii = 0; ii < 2; ++ii) {
                    s16x8 bf = *(const s16x8*)(FIT + m * 4096 +
                                (ii * 16 + l15) * 128 + ((ch ^ swz) * 16));
                    g[m][ii] = __builtin_amdgcn_mfma_f32_16x16x32_bf16(
                        a, bf, g[m][ii], 0, 0, 0);
                }
            }
        }

        __syncthreads();                    // all FjT reads complete
        if (sub < 3) stage_tile(sub + 1, bi ^ 1);   // refill FjT + V/R[bi^1]

        // ---- epilogue (overlaps the stage latency) ----
#pragma unroll
        for (int reg = 0; reg < 4; ++reg) {
            const int jl = wv * 16 + lg * 4 + reg;
            float rj0 = RJB(bi)[0 * 64 + jl];
            float rj1 = RJB(bi)[1 * 64 + jl];
            float rj2 = RJB(bi)[2 * 64 + jl];
            float u0[2], u1[2], u2[2];
#pragma unroll
            for (int ii = 0; ii < 2; ++ii) {
                float t0 = fmaxf(ri0[ii] + rj0 - 2.f * g[0][ii][reg], 0.f);
                float t1 = fmaxf(ri1[ii] + rj1 - 2.f * g[1][ii][reg], 0.f);
                float t2 = fmaxf(ri2[ii] + rj2 - 2.f * g[2][ii][reg], 0.f);
                float a0 = __expf(-t0 * inv0);
                float a1 = __expf(-t1 * inv1);
                float a2 = __expf(-t2 * inv2);
                u0[ii] = fmaf(c00, a0, fmaf(c01, a1, c02 * a2));
                u1[ii] = fmaf(c10, a0, fmaf(c11, a1, c12 * a2));
                u2[ii] = fmaf(c20, a0, fmaf(c21, a1, c22 * a2));
            }
            const float* vp0 = &VJB(bi)[(0 * 64 + jl) * 8];
            const float* vp1 = &VJB(bi)[(1 * 64 + jl) * 8];
            const float* vp2 = &VJB(bi)[(2 * 64 + jl) * 8];
            f32x4 v0a = *(const f32x4*)vp0, v0b = *(const f32x4*)(vp0 + 4);
            f32x4 v1a = *(const f32x4*)vp1, v1b = *(const f32x4*)(vp1 + 4);
            f32x4 v2a = *(const f32x4*)vp2, v2b = *(const f32x4*)(vp2 + 4);
#pragma unroll
            for (int ii = 0; ii < 2; ++ii) {
#pragma unroll
                for (int k = 0; k < 4; ++k) {
                    pv[0][ii][k]     = fmaf(u0[ii], v0a[k], pv[0][ii][k]);
                    pv[0][ii][k + 4] = fmaf(u0[ii], v0b[k], pv[0][ii][k + 4]);
                    pv[1][ii][k]     = fmaf(u1[ii], v1a[k], pv[1][ii][k]);
                    pv[1][ii][k + 4] = fmaf(u1[ii], v1b[k], pv[1][ii][k + 4]);
                    pv[2][ii][k]     = fmaf(u2[ii], v2a[k], pv[2][ii][k]);
                    pv[2][ii][k + 4] = fmaf(u2[ii], v2b[k], pv[2][ii][k + 4]);
                }
            }
        }
        __syncthreads();                    // stage writes landed
    }

#pragma unroll
    for (int mp = 0; mp < 3; ++mp)
#pragma unroll
        for (int ii = 0; ii < 2; ++ii)
#pragma unroll
            for (int k = 0; k < 8; ++k) {
                float v = pv[mp][ii][k];
                v += __shfl_xor(v, 16);
                v += __shfl_xor(v, 32);
                pv[mp][ii][k] = v;
            }

    float* P2 = (float*)smem;   // reuse FjT area: [wave][32 i][3 m][8 k]
    if (lane < 16) {
#pragma unroll
        for (int ii = 0; ii < 2; ++ii)
#pragma unroll
            for (int mp = 0; mp < 3; ++mp) {
                float* dst = &P2[((wv * 32) + ii * 16 + l15) * 24 + mp * 8];
#pragma unroll
                for (int k = 0; k < 8; ++k) dst[k] = pv[mp][ii][k];
            }
    }
    __syncthreads();
    for (int e = tid; e < 768; e += 256) {
        int i = e / 24, mk = e % 24, mp = mk >> 3, k = mk & 7;
        float s = P2[(0 * 32 + i) * 24 + mk] + P2[(1 * 32 + i) * 24 + mk] +
                  P2[(2 * 32 + i) * 24 + mk] + P2[(3 * 32 + i) * 24 + mk];
        atomicAdd(&attbuf[((mp * 4 + b) * HW + i0 + i) * 8 + k], s * gam[3 + mp]);
    }
}

// ---------------------------------------------------------------------------
// out[m][b][c][j] = d_m[b][c][j] * (att_m[b][j][:] . Wo[c][:] + bo[c]) + edge[b][j]
// ---------------------------------------------------------------------------
__global__ __launch_bounds__(256) void final_kernel(
    const float* __restrict__ d1, const float* __restrict__ d2,
    const float* __restrict__ d3, const float* __restrict__ attbuf,
    const float* __restrict__ Wo, const float* __restrict__ bo,
    const float* __restrict__ edge, float* __restrict__ out) {
    int blk = blockIdx.x;  // 3*4*64*9 = 6912
    int jt = blk % 9;
    int c = (blk / 9) % 64;
    int b = (blk / (9 * 64)) % 4;
    int m = blk / (9 * 64 * 4);
    int j = jt * 256 + threadIdx.x;
    const float* dm = (m == 0) ? d1 : (m == 1) ? d2 : d3;
    const float* ap = attbuf + ((m * 4 + b) * HW + j) * 8;
    float4 aa = *(const float4*)ap, ab = *(const float4*)(ap + 4);
    float av[8] = {aa.x, aa.y, aa.z, aa.w, ab.x, ab.y, ab.z, ab.w};
    float s = bo[c];
#pragma unroll
    for (int k = 0; k < 8; k++) s = fmaf(av[k], Wo[c * 8 + k], s);
    float val = fmaf(dm[(b * 64 + c) * HW + j], s, edge[b * HW + j]);
    out[((m * 4 + b) * 64 + c) * HW + j] = val;
}

// ---------------------------------------------------------------------------
extern "C" void kernel_launch(void* const* d_in, const int* in_sizes, int n_in,
                              void* d_out, int out_size, void* d_ws, size_t ws_size,
                              hipStream_t stream) {
    (void)in_sizes; (void)n_in; (void)out_size; (void)ws_size;
    const float* x1   = (const float*)d_in[0];
    const float* x2   = (const float*)d_in[1];
    const float* x3   = (const float*)d_in[2];
    const float* Wc1  = (const float*)d_in[3];
    const float* bc1  = (const float*)d_in[4];
    const float* Wc2  = (const float*)d_in[5];
    const float* bc2  = (const float*)d_in[6];
    const float* Wc3  = (const float*)d_in[7];
    const float* bc3  = (const float*)d_in[8];
    const float* bnf_g = (const float*)d_in[9];
    const float* bnf_b = (const float*)d_in[10];
    const float* bnf_m = (const float*)d_in[11];
    const float* bnf_v = (const float*)d_in[12];
    const float* Wm   = (const float*)d_in[13];
    const float* bm   = (const float*)d_in[14];
    const float* bnm_g = (const float*)d_in[15];
    const float* bnm_b = (const float*)d_in[16];
    const float* bnm_m = (const float*)d_in[17];
    const float* bnm_v = (const float*)d_in[18];
    const float* Wv   = (const float*)d_in[19];
    const float* bv   = (const float*)d_in[20];
    const float* Wo   = (const float*)d_in[21];
    const float* bo   = (const float*)d_in[22];
    const float* gam  = (const float*)d_in[23];

    float* ws = (float*)d_ws;
    float* A1 = ws;
    float* A2 = A1 + NB;
    float* B1 = A2 + NB;
    float* B2 = B1 + NB;
    float* C1 = B2 + NB;
    float* C2 = C1 + NB;
    float* edge = C2 + NB;                 // 4*2304
    float* vbuf = edge + 4 * HW;           // 3*4*2304*8
    float* rbuf = vbuf + 3 * 4 * HW * 8;   // 3*4*2304
    float* attb = rbuf + 3 * 4 * HW;       // 221184  <- zero region starts here
    float* accX = attb + 3 * 4 * HW * 8;   // 589824  (conv144 partials)
    float* accA = accX + NB;               // 3*NB    (conv64 step0 partials)
    float* accB = accA + 3 * NB;           // 3*NB    (conv64 step1 partials)
    unsigned short* dT = (unsigned short*)(accB + 3 * NB);  // 3*4*2304*64 bf16

    edge_kernel<<<36, 256, 0, stream>>>(x3, edge);
    // zero attb+accX+accA+accB: 221184+589824+1769472*2 = 4349952 floats
    zero_kernel<<<4248, 256, 0, stream>>>((float4*)attb);

    conv144_split<<<1152, 256, 0, stream>>>(x1, Wc1, accX);
    conv_first<21><<<1152, 256, 0, stream>>>(x2, Wc2, bc2, bnf_g + 64, bnf_b + 64, bnf_m + 64, bnf_v + 64, B1);
    conv_first<1><<<1152, 256, 0, stream>>>(x3, Wc3, bc3, bnf_g + 128, bnf_b + 128, bnf_m + 128, bnf_v + 128, C1);
    bn1_kernel<<<2304, 256, 0, stream>>>(accX, bc1, bnf_g, bnf_b, bnf_m, bnf_v, A1);

    conv64_split<<<1728, 256, 0, stream>>>(A1, B1, C1, accA, Wm, 0);
    bn64_kernel<<<6912, 256, 0, stream>>>(accA, bm, bnm_g, bnm_b, bnm_m, bnm_v, 0, A2, B2, C2);
    conv64_split<<<1728, 256, 0, stream>>>(A2, B2, C2, accB, Wm, 1);
    bn64_kernel<<<6912, 256, 0, stream>>>(accB, bm, bnm_g, bnm_b, bnm_m, bnm_v, 1, A1, B1, C1);

    value_r_kernel<<<432, 256, 0, stream>>>(A1, B1, C1, Wv, bv, vbuf, rbuf, dT);
    attn_kernel<<<2592, 256, 0, stream>>>(dT, vbuf, rbuf, gam, attb);
    final_kernel<<<6912, 256, 0, stream>>>(A1, B1, C1, attb, Wo, bo, edge, (float*)d_out);
}

// Round 15
// 486.038 us; speedup vs baseline: 1.0809x; 1.0809x over previous
//
#include <hip/hip_runtime.h>

#define HW 2304   // 48*48
#define NB (4 * 64 * HW)

typedef short s16x8 __attribute__((ext_vector_type(8)));
typedef float f32x4 __attribute__((ext_vector_type(4)));

static __device__ __forceinline__ unsigned short f2bf(float f) {
    unsigned u = __float_as_uint(f);
    unsigned r = (u + 0x7FFFu + ((u >> 16) & 1u)) >> 16;   // RNE
    return (unsigned short)r;
}

// ---------------------------------------------------------------------------
// Zero attb + accX + accA + accB (contiguous): 4349952 floats = 4248 blocks.
// ---------------------------------------------------------------------------
__global__ __launch_bounds__(256) void zero_kernel(float4* __restrict__ p) {
    p[blockIdx.x * 256 + threadIdx.x] = make_float4(0.f, 0.f, 0.f, 0.f);
}

// ---------------------------------------------------------------------------
// Sobel edge magnitude on x3 (C=1), SAME zero padding.  [4,48,48] -> [4,2304]
// ---------------------------------------------------------------------------
__global__ __launch_bounds__(256) void edge_kernel(const float* __restrict__ x3,
                                                   float* __restrict__ edge) {
    int idx = blockIdx.x * 256 + threadIdx.x;   // < 9216
    int b = idx / HW;
    int j = idx % HW;
    int y = j / 48, x = j % 48;
    const float* p = x3 + b * HW;
    auto at = [&](int yy, int xx) -> float {
        return (yy >= 0 && yy < 48 && xx >= 0 && xx < 48) ? p[yy * 48 + xx] : 0.f;
    };
    float a00 = at(y - 1, x - 1), a01 = at(y - 1, x), a02 = at(y - 1, x + 1);
    float a10 = at(y, x - 1),                         a12 = at(y, x + 1);
    float a20 = at(y + 1, x - 1), a21 = at(y + 1, x), a22 = at(y + 1, x + 1);
    float ex = (a02 - a00) + 2.f * (a12 - a10) + (a22 - a20);
    float ey = (a20 - a00) + 2.f * (a21 - a01) + (a22 - a02);
    edge[idx] = sqrtf(ex * ex + ey * ey);
}

// ---------------------------------------------------------------------------
// Chunked double-buffered conv body (R11 form) for small CIN (21/1).
// ---------------------------------------------------------------------------
template <int CIN, int NC>
__device__ __forceinline__ void conv_body(
    const float* __restrict__ in, const float* __restrict__ w,
    const float* __restrict__ bias,
    const float* __restrict__ bng, const float* __restrict__ bnb,
    const float* __restrict__ bnm, const float* __restrict__ bnv,
    float* __restrict__ out, int cg, int tile, int b) {
    const int tx0 = (tile % 3) * 16, ty0 = (tile / 3) * 16;
    const int tid = threadIdx.x;
    const int tx = tid & 15, ty = tid >> 4;

    __shared__ float sl[2][2880];   // [buf][8 cin][18][20]

    int goff[11], loff[11], clv[11];
#pragma unroll
    for (int t = 0; t < 11; ++t) {
        int e = tid + t * 256;
        int cl = e / 324; int r = e - cl * 324;
        int ly = r / 18;  int lx = r - ly * 18;
        int gy = ty0 + ly - 1, gx = tx0 + lx - 1;
        bool live = (e < 2592);
        bool inb = live && gy >= 0 && gy < 48 && gx >= 0 && gx < 48;
        goff[t] = inb ? (gy * 48 + gx) : -1;
        loff[t] = live ? (cl * 360 + ly * 20 + lx) : -1;
        clv[t] = cl;
    }

    auto stage = [&](int c0, int bf) {
#pragma unroll
        for (int t = 0; t < 11; ++t) {
            if (loff[t] >= 0) {
                int cin = c0 + clv[t];
                float v = 0.f;
                if (goff[t] >= 0 && (CIN % 8 == 0 || cin < CIN))
                    v = in[(b * CIN + cin) * HW + goff[t]];
                sl[bf][loff[t]] = v;
            }
        }
    };

    float acc[NC];
#pragma unroll
    for (int k = 0; k < NC; ++k) acc[k] = 0.f;

    auto compute = [&](int c0, int bf) {
#pragma unroll
        for (int cl = 0; cl < 8; ++cl) {
            if (CIN % 8 != 0 && c0 + cl >= CIN) continue;
            float xv[9];
#pragma unroll
            for (int dy = 0; dy < 3; dy++)
#pragma unroll
                for (int dx = 0; dx < 3; dx++)
                    xv[dy * 3 + dx] = sl[bf][cl * 360 + (ty + dy) * 20 + (tx + dx)];
#pragma unroll
            for (int k = 0; k < NC; ++k) {
                const float* wk = w + ((cg * NC + k) * CIN + (c0 + cl)) * 9;
                float a = acc[k];
#pragma unroll
                for (int d = 0; d < 9; ++d) a = fmaf(wk[d], xv[d], a);
                acc[k] = a;
            }
        }
    };

    constexpr int NCH = (CIN + 7) / 8;
    stage(0, 0);
    __syncthreads();
#pragma unroll 1
    for (int ch = 0; ch < NCH; ++ch) {
        if (ch + 1 < NCH) stage((ch + 1) * 8, (ch + 1) & 1);
        compute(ch * 8, ch & 1);
        __syncthreads();
    }

    const int oy = ty0 + ty, ox = tx0 + tx;
#pragma unroll
    for (int k = 0; k < NC; ++k) {
        int o = cg * NC + k;
        float sc = bng[o] * rsqrtf(bnv[o] + 1e-5f);
        float sh = bnb[o] - bnm[o] * sc;
        float y = fmaf(acc[k] + bias[o], sc, sh);
        y = y > 0.f ? y : 0.01f * y;
        out[(b * 64 + o) * HW + oy * 48 + ox] = y;
    }
}

// Small first-layer convs (CIN 21/1): NC=4 -> grid 576.  (R11 form)
template <int CIN>
__global__ __launch_bounds__(256) void conv_first(
    const float* __restrict__ in, const float* __restrict__ w,
    const float* __restrict__ bias,
    const float* __restrict__ bng, const float* __restrict__ bnb,
    const float* __restrict__ bnm, const float* __restrict__ bnv,
    float* __restrict__ out) {
    int lb = blockIdx.x;
    int blk = (lb & 7) * 72 + (lb >> 3);   // 576 = 8 * 72
    int cg = blk & 15, tile = (blk >> 4) % 9, b = blk / 144;
    conv_body<CIN, 4>(in, w, bias, bng, bnb, bnm, bnv, out, cg, tile, b);
}

// ---------------------------------------------------------------------------
// conv144_split (R11 form): 4-way cin-split x NC=8, chunked double-buffered,
// grid 1152; raw partials atomicAdd'ed into zeroed accX; bn1 finishes.
// ---------------------------------------------------------------------------
__global__ __launch_bounds__(256) void conv144_split(
    const float* __restrict__ in, const float* __restrict__ w,
    float* __restrict__ acc_out) {
    int lb = blockIdx.x;
    int blk = (lb & 7) * 144 + (lb >> 3);   // 1152 = 8 * 144
    const int sp   = blk & 3;               // cin split (36 each)
    const int cg   = (blk >> 2) & 7;        // cout group of 8
    const int tile = (blk >> 5) % 9;
    const int b    = blk / 288;
    const int tx0 = (tile % 3) * 16, ty0 = (tile / 3) * 16;
    const int tid = threadIdx.x;
    const int tx = tid & 15, ty = tid >> 4;

    __shared__ float sl[2][2880];

    int goff[11], loff[11], clv[11];
#pragma unroll
    for (int t = 0; t < 11; ++t) {
        int e = tid + t * 256;
        int cl = e / 324; int r = e - cl * 324;
        int ly = r / 18;  int lx = r - ly * 18;
        int gy = ty0 + ly - 1, gx = tx0 + lx - 1;
        bool live = (e < 2592);
        bool inb = live && gy >= 0 && gy < 48 && gx >= 0 && gx < 48;
        goff[t] = inb ? (gy * 48 + gx) : -1;
        loff[t] = live ? (cl * 360 + ly * 20 + lx) : -1;
        clv[t] = cl;
    }

    const float* inb_p = in + (b * 144 + sp * 36) * HW;

    auto stage = [&](int c0, int bf) {
#pragma unroll
        for (int t = 0; t < 11; ++t) {
            if (loff[t] >= 0) {
                int cin = c0 + clv[t];
                float v = 0.f;
                if (goff[t] >= 0 && cin < 36) v = inb_p[cin * HW + goff[t]];
                sl[bf][loff[t]] = v;
            }
        }
    };

    float acc[8];
#pragma unroll
    for (int k = 0; k < 8; ++k) acc[k] = 0.f;

    auto compute = [&](int c0, int bf) {
#pragma unroll
        for (int cl = 0; cl < 8; ++cl) {
            if (c0 + cl >= 36) continue;
            float xv[9];
#pragma unroll
            for (int dy = 0; dy < 3; dy++)
#pragma unroll
                for (int dx = 0; dx < 3; dx++)
                    xv[dy * 3 + dx] = sl[bf][cl * 360 + (ty + dy) * 20 + (tx + dx)];
#pragma unroll
            for (int k = 0; k < 8; ++k) {
                const float* wk = w + ((cg * 8 + k) * 144 + sp * 36 + c0 + cl) * 9;
                float a = acc[k];
#pragma unroll
                for (int d = 0; d < 9; ++d) a = fmaf(wk[d], xv[d], a);
                acc[k] = a;
            }
        }
    };

    stage(0, 0);
    __syncthreads();
#pragma unroll 1
    for (int ch = 0; ch < 5; ++ch) {       // 36 cins = 5 chunks (last = 4)
        if (ch + 1 < 5) stage((ch + 1) * 8, (ch + 1) & 1);
        compute(ch * 8, ch & 1);
        __syncthreads();
    }

    const int oy = ty0 + ty, ox = tx0 + tx;
#pragma unroll
    for (int k = 0; k < 8; ++k)
        atomicAdd(&acc_out[(b * 64 + cg * 8 + k) * HW + oy * 48 + ox], acc[k]);
}

// BN + LeakyReLU for the accumulated 144-conv.  589824 elems -> 2304 blocks.
__global__ __launch_bounds__(256) void bn1_kernel(
    const float* __restrict__ acc, const float* __restrict__ bias,
    const float* __restrict__ bng, const float* __restrict__ bnb,
    const float* __restrict__ bnm, const float* __restrict__ bnv,
    float* __restrict__ out) {
    int idx = blockIdx.x * 256 + threadIdx.x;
    int o = (idx / HW) & 63;
    float sc = bng[o] * rsqrtf(bnv[o] + 1e-5f);
    float sh = bnb[o] - bnm[o] * sc;
    float y = fmaf(acc[idx] + bias[o], sc, sh);
    out[idx] = y > 0.f ? y : 0.01f * y;
}

// ---------------------------------------------------------------------------
// conv64_split (R13): 3 horizontal px/thread on a 48x16 full-width tile.
// 15 LDS reads feed 216 FMAs per cin (was 9:72) -> 3x weight/LDS amortization.
// 4-way cin-split (16 each) keeps grid at 1152; 4-cin chunks double-buffered
// (28.8 KB LDS).  Raw partials atomicAdd'ed; bn64 finishes.
// ---------------------------------------------------------------------------
__global__ __launch_bounds__(256) void conv64_split(
    const float* __restrict__ inA, const float* __restrict__ inB,
    const float* __restrict__ inC, float* __restrict__ acc_out,
    const float* __restrict__ Wm, int step) {
    int lb = blockIdx.x;
    int blk = (lb & 7) * 144 + (lb >> 3);  // 1152 = 8 * 144
    const int br = blk / 384;
    int rr = blk - br * 384;
    const int sp = rr & 3;                 // cin split (16 each)
    const int cg = (rr >> 2) & 7;          // cout group of 8
    const int yt = (rr >> 5) % 3;          // row tile (16 rows)
    const int b  = rr / 96;
    const int y0 = yt * 16;
    const int tid = threadIdx.x;
    const int tx = tid & 15, ty = tid >> 4;   // px: x = 3*tx+p, y = y0+ty

    const float* in = (br == 0) ? inA : (br == 1) ? inB : inC;
    const float* w = Wm + (2 * br + step) * (64 * 64 * 9);
    const float* ip = in + (b * 64 + sp * 16) * HW;

    __shared__ float sl[2][3600];          // [buf][4 cin][18 rows][50 cols]

    auto stage = [&](int c0, int bf) {
        for (int e = tid; e < 3600; e += 256) {
            int cl = e / 900; int r = e - cl * 900;
            int ly = r / 50;  int lx = r - ly * 50;
            int gy = y0 + ly - 1, gx = lx - 1;
            float v = 0.f;
            if (gy >= 0 && gy < 48 && gx >= 0 && gx < 48)
                v = ip[(c0 + cl) * HW + gy * 48 + gx];
            sl[bf][e] = v;                 // e == cl*900 + ly*50 + lx
        }
    };

    float acc[8][3];
#pragma unroll
    for (int k = 0; k < 8; ++k)
#pragma unroll
        for (int p = 0; p < 3; ++p) acc[k][p] = 0.f;

    auto compute = [&](int c0, int bf) {
#pragma unroll
        for (int cl = 0; cl < 4; ++cl) {
            float xv[15];
#pragma unroll
            for (int dy = 0; dy < 3; ++dy)
#pragma unroll
                for (int c = 0; c < 5; ++c)
                    xv[dy * 5 + c] = sl[bf][cl * 900 + (ty + dy) * 50 + 3 * tx + c];
#pragma unroll
            for (int k = 0; k < 8; ++k) {
                const float* wk = w + ((cg * 8 + k) * 64 + sp * 16 + c0 + cl) * 9;
#pragma unroll
                for (int dy = 0; dy < 3; ++dy)
#pragma unroll
                    for (int dx = 0; dx < 3; ++dx) {
                        float wv = wk[dy * 3 + dx];
#pragma unroll
                        for (int p = 0; p < 3; ++p)
                            acc[k][p] = fmaf(wv, xv[dy * 5 + p + dx], acc[k][p]);
                    }
            }
        }
    };

    stage(0, 0);
    __syncthreads();
#pragma unroll 1
    for (int ch = 0; ch < 4; ++ch) {       // 16 cins = 4 chunks of 4
        if (ch + 1 < 4) stage((ch + 1) * 4, (ch + 1) & 1);
        compute(ch * 4, ch & 1);
        __syncthreads();
    }

    const int oy = y0 + ty, ox = 3 * tx;
    float* dst = acc_out + br * NB + (b * 64 + cg * 8) * HW + oy * 48 + ox;
#pragma unroll
    for (int k = 0; k < 8; ++k)
#pragma unroll
        for (int p = 0; p < 3; ++p)
            atomicAdd(dst + k * HW + p, acc[k][p]);
}

// BN + LeakyReLU for the accumulated 64-convs (3 branches).  Grid 6912.
__global__ __launch_bounds__(256) void bn64_kernel(
    const float* __restrict__ acc, const float* __restrict__ bm,
    const float* __restrict__ bng, const float* __restrict__ bnb,
    const float* __restrict__ bnm, const float* __restrict__ bnv, int step,
    float* __restrict__ oA, float* __restrict__ oB, float* __restrict__ oC) {
    int idx = blockIdx.x * 256 + threadIdx.x;   // < 3*NB
    int br = idx / NB;
    int rem = idx - br * NB;
    int oo = (2 * br + step) * 64 + ((rem / HW) & 63);
    float sc = bng[oo] * rsqrtf(bnv[oo] + 1e-5f);
    float sh = bnb[oo] - bnm[oo] * sc;
    float y = fmaf(acc[idx] + bm[oo], sc, sh);
    y = y > 0.f ? y : 0.01f * y;
    float* out = (br == 0) ? oA : (br == 1) ? oB : oC;
    out[rem] = y;
}

// ---------------------------------------------------------------------------
// value_r_kernel: value vectors (1x1 conv 64->8), squared norms, and the
// pre-swizzled transposed bf16 feature tensor dT[m][b][j][c] (row = 128 B).
// ---------------------------------------------------------------------------
__global__ __launch_bounds__(256) void value_r_kernel(
    const float* __restrict__ d1, const float* __restrict__ d2,
    const float* __restrict__ d3, const float* __restrict__ Wv,
    const float* __restrict__ bv, float* __restrict__ vbuf,
    float* __restrict__ rbuf, unsigned short* __restrict__ dT) {
    __shared__ float sWv[512];
    int blk = blockIdx.x;
    int jseg = blk % 36;
    int b = (blk / 36) % 4;
    int m = blk / 144;
    int tid = threadIdx.x;
    sWv[tid] = Wv[tid];
    if (tid < 256) sWv[tid + 256] = Wv[tid + 256];
    __syncthreads();

    int jl = tid >> 2, cp = tid & 3;
    int j = jseg * 64 + jl;
    const float* dm = (m == 0) ? d1 : (m == 1) ? d2 : d3;
    const float* dp = dm + (b * 64) * HW + j;
    float acc[8];
#pragma unroll
    for (int k = 0; k < 8; k++) acc[k] = 0.f;
    float r = 0.f;
    float x[16];
#pragma unroll
    for (int cc = 0; cc < 16; ++cc) {
        int c = cp * 16 + cc;
        float xv = dp[c * HW];
        x[cc] = xv;
        r = fmaf(xv, xv, r);
#pragma unroll
        for (int k = 0; k < 8; k++) acc[k] = fmaf(xv, sWv[k * 64 + c], acc[k]);
    }

    {
        unsigned wds[8];
#pragma unroll
        for (int t = 0; t < 8; ++t)
            wds[t] = (unsigned)f2bf(x[2 * t]) | ((unsigned)f2bf(x[2 * t + 1]) << 16);
        size_t rowb = ((size_t)(m * 4 + b) * HW + j) * 128;   // bytes
        int s = jl & 7;                                        // == j & 7
        uint4 p0 = make_uint4(wds[0], wds[1], wds[2], wds[3]);
        uint4 p1 = make_uint4(wds[4], wds[5], wds[6], wds[7]);
        *(uint4*)((char*)dT + rowb + (size_t)(((cp * 2) ^ s) * 16)) = p0;
        *(uint4*)((char*)dT + rowb + (size_t)(((cp * 2 + 1) ^ s) * 16)) = p1;
    }

    r += __shfl_xor(r, 1, 4);
    r += __shfl_xor(r, 2, 4);
    float* vp = vbuf + ((m * 4 + b) * HW + j) * 8;
#pragma unroll
    for (int k = 0; k < 8; k++) {
        float v = acc[k];
        v += __shfl_xor(v, 1, 4);
        v += __shfl_xor(v, 2, 4);
        if (cp == 0) vp[k] = v + bv[k];
    }
    if (cp == 0) rbuf[(m * 4 + b) * HW + j] = r;
}

// ---------------------------------------------------------------------------
// attn v5: MFMA Gram + VALU epilogue/PV.  Single-buffered FjT (49.9 KB LDS,
// 3 blocks/CU); per subtile: Gram -> barrier -> stage(sub+1) -> epilogue
// (overlaps stage latency) -> barrier.  V/R double-buffered.
// ---------------------------------------------------------------------------
#define FJT   (smem)
#define FIT   (smem + 24576)
#define VJB(bi) ((float*)(smem + 36864 + (bi) * 6144))
#define RJB(bi) ((float*)(smem + 49152 + (bi) * 768))

__global__ __launch_bounds__(256, 2) void attn_kernel(
    const unsigned short* __restrict__ dT, const float* __restrict__ vbuf,
    const float* __restrict__ rbuf, const float* __restrict__ gam,
    float* __restrict__ attbuf) {
    __shared__ char smem[51072];
    float* Ri = (float*)(smem + 50688);  // 384 B

    int lb = blockIdx.x;
    int blk = (lb & 7) * 324 + (lb >> 3);
    const int js = blk % 9;
    const int it = (blk / 9) % 72;
    const int b  = blk / 648;
    const int i0 = it * 32;
    const int tid = threadIdx.x;
    const int lane = tid & 63;
    const int wv = tid >> 6;
    const int l15 = lane & 15, lg = lane >> 4;
    const int swz = l15 & 7;

    // ---- stage FiT (12 x 1KB) + Ri (once) ----
#pragma unroll
    for (int t = 0; t < 3; ++t) {
        int ck = wv * 3 + t;
        int m = ck >> 2; int off = (ck & 3) * 1024;
        const char* src = (const char*)dT +
            ((size_t)((m * 4 + b) * HW + i0) * 128) + off + lane * 16;
        __builtin_amdgcn_global_load_lds((const unsigned int*)src,
                                         (unsigned int*)(FIT + ck * 1024), 16, 0, 0);
    }
    if (tid < 96) {
        int m = tid >> 5, i = tid & 31;
        Ri[m * 32 + i] = rbuf[(m * 4 + b) * HW + i0 + i];
    }

    auto stage_tile = [&](int sub, int bi) {
        const int j0 = (js * 4 + sub) * 64;
#pragma unroll
        for (int t = 0; t < 8; ++t) {
            int idx = t * 4 + wv;
            if (idx < 24) {                      // FjT: 24 x 1KB (single buf)
                int m = idx >> 3; int off = (idx & 7) * 1024;
                const char* src = (const char*)dT +
                    ((size_t)((m * 4 + b) * HW + j0) * 128) + off + lane * 16;
                __builtin_amdgcn_global_load_lds((const unsigned int*)src,
                    (unsigned int*)(FJT + idx * 1024), 16, 0, 0);
            } else if (idx < 30) {               // Vj: 6 x 1KB (double buf)
                int c = idx - 24; int m = c >> 1; int off = (c & 1) * 1024;
                const char* src = (const char*)vbuf +
                    ((size_t)((m * 4 + b) * HW + j0) * 32) + off + lane * 16;
                __builtin_amdgcn_global_load_lds((const unsigned int*)src,
                    (unsigned int*)((char*)VJB(bi) + c * 1024), 16, 0, 0);
            }
        }
        if (tid < 192) {
            int m = tid >> 6, jl = tid & 63;
            RJB(bi)[m * 64 + jl] = rbuf[(m * 4 + b) * HW + j0 + jl];
        }
    };

    float g0 = gam[0], g1 = gam[1], g2 = gam[2];
    float inv0 = 1.f / (2.f * g0 * g0);
    float inv1 = 1.f / (2.f * g1 * g1);
    float inv2 = 1.f / (2.f * g2 * g2);
    float g6 = gam[6], g7 = gam[7], g8 = gam[8];
    float c00 = g6,       c01 = g7 + 1.f, c02 = g8 + 1.f;
    float c10 = g6 + 1.f, c11 = g7,       c12 = g8 + 1.f;
    float c20 = g6 + 1.f, c21 = g7 + 1.f, c22 = g8;

    stage_tile(0, 0);
    __syncthreads();    // drains global_load_lds

    float ri0[2], ri1[2], ri2[2];
#pragma unroll
    for (int ii = 0; ii < 2; ++ii) {
        ri0[ii] = Ri[0 * 32 + ii * 16 + l15];
        ri1[ii] = Ri[1 * 32 + ii * 16 + l15];
        ri2[ii] = Ri[2 * 32 + ii * 16 + l15];
    }

    float pv[3][2][8];
#pragma unroll
    for (int mp = 0; mp < 3; ++mp)
#pragma unroll
        for (int ii = 0; ii < 2; ++ii)
#pragma unroll
            for (int k = 0; k < 8; ++k) pv[mp][ii][k] = 0.f;

#pragma unroll 1
    for (int sub = 0; sub < 4; ++sub) {
        const int bi = sub & 1;

        // ---- Gram MFMA from the (single) FjT + FiT ----
        f32x4 g[3][2];
#pragma unroll
        for (int m = 0; m < 3; ++m)
#pragma unroll
            for (int ii = 0; ii < 2; ++ii) g[m][ii] = (f32x4){0.f, 0.f, 0.f, 0.f};

#pragma unroll
        for (int m = 0; m < 3; ++m) {
#pragma unroll
            for (int slab = 0; slab < 2; ++slab) {
                int ch = slab * 4 + lg;
                s16x8 a = *(const s16x8*)(FJT + m * 8192 +
                            (wv * 16 + l15) * 128 + ((ch ^ swz) * 16));
#pragma unroll
                for (int ii = 0; ii < 2; ++ii) {
                    s16x8 bf = *(const s16x8*)(FIT + m * 4096 +
                                (ii * 16 + l15) * 128 + ((ch ^ swz) * 16));
                    g[m][ii] = __builtin_amdgcn_mfma_f32_16x16x32_bf16(
                        a, bf, g[m][ii], 0, 0, 0);
                }
            }
        }

        __syncthreads();                    // all FjT reads complete
        if (sub < 3) stage_tile(sub + 1, bi ^ 1);   // refill FjT + V/R[bi^1]

        // ---- epilogue (overlaps the stage latency) ----
#pragma unroll
        for (int reg = 0; reg < 4; ++reg) {
            const int jl = wv * 16 + lg * 4 + reg;
            float rj0 = RJB(bi)[0 * 64 + jl];
            float rj1 = RJB(bi)[1 * 64 + jl];
            float rj2 = RJB(bi)[2 * 64 + jl];
            float u0[2], u1[2], u2[2];
#pragma unroll
            for (int ii = 0; ii < 2; ++ii) {
                float t0 = fmaxf(ri0[ii] + rj0 - 2.f * g[0][ii][reg], 0.f);
                float t1 = fmaxf(ri1[ii] + rj1 - 2.f * g[1][ii][reg], 0.f);
                float t2 = fmaxf(ri2[ii] + rj2 - 2.f * g[2][ii][reg], 0.f);
                float a0 = __expf(-t0 * inv0);
                float a1 = __expf(-t1 * inv1);
                float a2 = __expf(-t2 * inv2);
                u0[ii] = fmaf(c00, a0, fmaf(c01, a1, c02 * a2));
                u1[ii] = fmaf(c10, a0, fmaf(c11, a1, c12 * a2));
                u2[ii] = fmaf(c20, a0, fmaf(c21, a1, c22 * a2));
            }
            const float* vp0 = &VJB(bi)[(0 * 64 + jl) * 8];
            const float* vp1 = &VJB(bi)[(1 * 64 + jl) * 8];
            const float* vp2 = &VJB(bi)[(2 * 64 + jl) * 8];
            f32x4 v0a = *(const f32x4*)vp0, v0b = *(const f32x4*)(vp0 + 4);
            f32x4 v1a = *(const f32x4*)vp1, v1b = *(const f32x4*)(vp1 + 4);
            f32x4 v2a = *(const f32x4*)vp2, v2b = *(const f32x4*)(vp2 + 4);
#pragma unroll
            for (int ii = 0; ii < 2; ++ii) {
#pragma unroll
                for (int k = 0; k < 4; ++k) {
                    pv[0][ii][k]     = fmaf(u0[ii], v0a[k], pv[0][ii][k]);
                    pv[0][ii][k + 4] = fmaf(u0[ii], v0b[k], pv[0][ii][k + 4]);
                    pv[1][ii][k]     = fmaf(u1[ii], v1a[k], pv[1][ii][k]);
                    pv[1][ii][k + 4] = fmaf(u1[ii], v1b[k], pv[1][ii][k + 4]);
                    pv[2][ii][k]     = fmaf(u2[ii], v2a[k], pv[2][ii][k]);
                    pv[2][ii][k + 4] = fmaf(u2[ii], v2b[k], pv[2][ii][k + 4]);
                }
            }
        }
        __syncthreads();                    // stage writes landed
    }

#pragma unroll
    for (int mp = 0; mp < 3; ++mp)
#pragma unroll
        for (int ii = 0; ii < 2; ++ii)
#pragma unroll
            for (int k = 0; k < 8; ++k) {
                float v = pv[mp][ii][k];
                v += __shfl_xor(v, 16);
                v += __shfl_xor(v, 32);
                pv[mp][ii][k] = v;
            }

    float* P2 = (float*)smem;   // reuse FjT area: [wave][32 i][3 m][8 k]
    if (lane < 16) {
#pragma unroll
        for (int ii = 0; ii < 2; ++ii)
#pragma unroll
            for (int mp = 0; mp < 3; ++mp) {
                float* dst = &P2[((wv * 32) + ii * 16 + l15) * 24 + mp * 8];
#pragma unroll
                for (int k = 0; k < 8; ++k) dst[k] = pv[mp][ii][k];
            }
    }
    __syncthreads();
    for (int e = tid; e < 768; e += 256) {
        int i = e / 24, mk = e % 24, mp = mk >> 3, k = mk & 7;
        float s = P2[(0 * 32 + i) * 24 + mk] + P2[(1 * 32 + i) * 24 + mk] +
                  P2[(2 * 32 + i) * 24 + mk] + P2[(3 * 32 + i) * 24 + mk];
        atomicAdd(&attbuf[((mp * 4 + b) * HW + i0 + i) * 8 + k], s * gam[3 + mp]);
    }
}

// ---------------------------------------------------------------------------
// out[m][b][c][j] = d_m[b][c][j] * (att_m[b][j][:] . Wo[c][:] + bo[c]) + edge[b][j]
// ---------------------------------------------------------------------------
__global__ __launch_bounds__(256) void final_kernel(
    const float* __restrict__ d1, const float* __restrict__ d2,
    const float* __restrict__ d3, const float* __restrict__ attbuf,
    const float* __restrict__ Wo, const float* __restrict__ bo,
    const float* __restrict__ edge, float* __restrict__ out) {
    int blk = blockIdx.x;  // 3*4*64*9 = 6912
    int jt = blk % 9;
    int c = (blk / 9) % 64;
    int b = (blk / (9 * 64)) % 4;
    int m = blk / (9 * 64 * 4);
    int j = jt * 256 + threadIdx.x;
    const float* dm = (m == 0) ? d1 : (m == 1) ? d2 : d3;
    const float* ap = attbuf + ((m * 4 + b) * HW + j) * 8;
    float4 aa = *(const float4*)ap, ab = *(const float4*)(ap + 4);
    float av[8] = {aa.x, aa.y, aa.z, aa.w, ab.x, ab.y, ab.z, ab.w};
    float s = bo[c];
#pragma unroll
    for (int k = 0; k < 8; k++) s = fmaf(av[k], Wo[c * 8 + k], s);
    float val = fmaf(dm[(b * 64 + c) * HW + j], s, edge[b * HW + j]);
    out[((m * 4 + b) * 64 + c) * HW + j] = val;
}

// ---------------------------------------------------------------------------
extern "C" void kernel_launch(void* const* d_in, const int* in_sizes, int n_in,
                              void* d_out, int out_size, void* d_ws, size_t ws_size,
                              hipStream_t stream) {
    (void)in_sizes; (void)n_in; (void)out_size; (void)ws_size;
    const float* x1   = (const float*)d_in[0];
    const float* x2   = (const float*)d_in[1];
    const float* x3   = (const float*)d_in[2];
    const float* Wc1  = (const float*)d_in[3];
    const float* bc1  = (const float*)d_in[4];
    const float* Wc2  = (const float*)d_in[5];
    const float* bc2  = (const float*)d_in[6];
    const float* Wc3  = (const float*)d_in[7];
    const float* bc3  = (const float*)d_in[8];
    const float* bnf_g = (const float*)d_in[9];
    const float* bnf_b = (const float*)d_in[10];
    const float* bnf_m = (const float*)d_in[11];
    const float* bnf_v = (const float*)d_in[12];
    const float* Wm   = (const float*)d_in[13];
    const float* bm   = (const float*)d_in[14];
    const float* bnm_g = (const float*)d_in[15];
    const float* bnm_b = (const float*)d_in[16];
    const float* bnm_m = (const float*)d_in[17];
    const float* bnm_v = (const float*)d_in[18];
    const float* Wv   = (const float*)d_in[19];
    const float* bv   = (const float*)d_in[20];
    const float* Wo   = (const float*)d_in[21];
    const float* bo   = (const float*)d_in[22];
    const float* gam  = (const float*)d_in[23];

    float* ws = (float*)d_ws;
    float* A1 = ws;
    float* A2 = A1 + NB;
    float* B1 = A2 + NB;
    float* B2 = B1 + NB;
    float* C1 = B2 + NB;
    float* C2 = C1 + NB;
    float* edge = C2 + NB;                 // 4*2304
    float* vbuf = edge + 4 * HW;           // 3*4*2304*8
    float* rbuf = vbuf + 3 * 4 * HW * 8;   // 3*4*2304
    float* attb = rbuf + 3 * 4 * HW;       // 221184  <- zero region starts here
    float* accX = attb + 3 * 4 * HW * 8;   // 589824  (conv144 partials)
    float* accA = accX + NB;               // 3*NB    (conv64 step0 partials)
    float* accB = accA + 3 * NB;           // 3*NB    (conv64 step1 partials)
    unsigned short* dT = (unsigned short*)(accB + 3 * NB);  // 3*4*2304*64 bf16

    edge_kernel<<<36, 256, 0, stream>>>(x3, edge);
    // zero attb+accX+accA+accB: 221184+589824+1769472*2 = 4349952 floats
    zero_kernel<<<4248, 256, 0, stream>>>((float4*)attb);

    conv144_split<<<1152, 256, 0, stream>>>(x1, Wc1, accX);
    conv_first<21><<<576, 256, 0, stream>>>(x2, Wc2, bc2, bnf_g + 64, bnf_b + 64, bnf_m + 64, bnf_v + 64, B1);
    conv_first<1><<<576, 256, 0, stream>>>(x3, Wc3, bc3, bnf_g + 128, bnf_b + 128, bnf_m + 128, bnf_v + 128, C1);
    bn1_kernel<<<2304, 256, 0, stream>>>(accX, bc1, bnf_g, bnf_b, bnf_m, bnf_v, A1);

    conv64_split<<<1152, 256, 0, stream>>>(A1, B1, C1, accA, Wm, 0);
    bn64_kernel<<<6912, 256, 0, stream>>>(accA, bm, bnm_g, bnm_b, bnm_m, bnm_v, 0, A2, B2, C2);
    conv64_split<<<1152, 256, 0, stream>>>(A2, B2, C2, accB, Wm, 1);
    bn64_kernel<<<6912, 256, 0, stream>>>(accB, bm, bnm_g, bnm_b, bnm_m, bnm_v, 1, A1, B1, C1);

    value_r_kernel<<<432, 256, 0, stream>>>(A1, B1, C1, Wv, bv, vbuf, rbuf, dT);
    attn_kernel<<<2592, 256, 0, stream>>>(dT, vbuf, rbuf, gam, attb);
    final_kernel<<<6912, 256, 0, stream>>>(A1, B1, C1, attb, Wo, bo, edge, (float*)d_out);
}